// Round 8
// baseline (454.272 us; speedup 1.0000x reference)
//
#include <hip/hip_runtime.h>
#include <math.h>

#define BATCH 256
#define PRE   64     // k
#define NEXT  32     // K
#define DIN   128    // d
#define DOUT  64     // D

typedef __attribute__((ext_vector_type(8))) short bf16x8;
typedef __attribute__((ext_vector_type(4))) float f32x4;

__device__ __forceinline__ unsigned short f2bf(float f) {
    unsigned u = __float_as_uint(f);
    unsigned r = (u + 0x7fffu + ((u >> 16) & 1u)) >> 16;   // RNE
    return (unsigned short)r;
}
__device__ __forceinline__ float bf2f(unsigned short h) {
    return __uint_as_float(((unsigned)h) << 16);
}

#define WFRAG_S 10   // dwords per fragment slot (8 data + 2 pad)

// ---------------- MFMA GEMM -> p fp32, NATURAL [lb,k,K,D] layout --------------
// Grid (K=32, kk=64) — bt folded INTO the block (R7 lesson: bt as a grid dim
// read W twice = 268 MB HBM). Block stages all nbt*128 x-rows (40 KB LDS) and
// converts its 32x64 W slab once per dc; both row-halves consume it.
// 3-product split (xh*wh + xl*wh + xh*wl), in-LDS packed (h|l<<16) W frags.
__global__ __launch_bounds__(256, 3) void gemm_kernel(const float* __restrict__ x,
                                                      const float* __restrict__ W,
                                                      float* __restrict__ p,
                                                      int b0, int nbt)
{
    __shared__ float xs[256 * 40];              // 40 KB x-tile [row][d]
    __shared__ unsigned wpk[256 * WFRAG_S];     // 10 KB packed W frags
    const int K    = blockIdx.x;
    const int kk   = blockIdx.y;
    const int t    = threadIdx.x;
    const int wave = t >> 6;
    const int lane = t & 63;
    const int ln   = lane & 15;
    const int quad = lane >> 4;

    f32x4 acc[2][2][4];                          // [bt][mt][nt]
#pragma unroll
    for (int bt = 0; bt < 2; ++bt)
#pragma unroll
        for (int mt = 0; mt < 2; ++mt)
#pragma unroll
            for (int nt = 0; nt < 4; ++nt) acc[bt][mt][nt] = (f32x4){0.f, 0.f, 0.f, 0.f};

    const float*  Wk  = W + (size_t)(kk * NEXT + K) * DIN * DOUT;
    const float4* xg4 = (const float4*)x;

    for (int dc = 0; dc < 4; ++dc) {
        __syncthreads();
        // stage x tile: nbt*128 rows x 32 d (8 lanes/row: 128B contiguous)
        for (int i = 0; i < nbt * 4; ++i) {
            const int f   = t + 256 * i;
            const int row = f >> 3;
            const int d4  = f & 7;
            float4 v = xg4[((size_t)(b0 + row) * PRE + kk) * 32 + dc * 8 + d4];
            *(float4*)&xs[row * 40 + d4 * 4] = v;
        }
        // stage W slab 32x64, convert to packed bf16 hi|lo in fragment order
#pragma unroll
        for (int it = 0; it < 8; ++it) {
            const int e  = it * 256 + t;    // 0..2047
            const int dl = e >> 6;          // 0..31
            const int D  = e & 63;
            float v = Wk[(size_t)(dc * 32 + dl) * DOUT + D];
            unsigned short h = f2bf(v);
            unsigned short l = f2bf(v - bf2f(h));
            const int fr = ((D >> 4) * 64 + (dl >> 3) * 16 + (D & 15));
            wpk[fr * WFRAG_S + (dl & 7)] = (unsigned)h | ((unsigned)l << 16);
        }
        __syncthreads();

        // B fragments once per dc (shared by both row-halves)
        bf16x8 bh[4], bl[4];
#pragma unroll
        for (int nt = 0; nt < 4; ++nt) {
            const unsigned* wp = &wpk[(nt * 64 + quad * 16 + ln) * WFRAG_S];
            unsigned pk[8];
#pragma unroll
            for (int i2 = 0; i2 < 4; ++i2) *(uint2*)&pk[i2 * 2] = *(const uint2*)&wp[i2 * 2];
            union { bf16x8 v; unsigned u[4]; } BH, BL;
#pragma unroll
            for (int i2 = 0; i2 < 4; ++i2) {
                BH.u[i2] = (pk[2 * i2] & 0xffffu) | (pk[2 * i2 + 1] << 16);
                BL.u[i2] = (pk[2 * i2] >> 16) | (pk[2 * i2 + 1] & 0xffff0000u);
            }
            bh[nt] = BH.v; bl[nt] = BL.v;
        }

        for (int bt = 0; bt < nbt; ++bt) {
            // A fragments from xs + hi/lo split
            bf16x8 ah[2], al[2];
#pragma unroll
            for (int mt = 0; mt < 2; ++mt) {
                const float* xa = &xs[(bt * 128 + wave * 32 + mt * 16 + ln) * 40 + quad * 8];
                float4 v0 = *(const float4*)xa;
                float4 v1 = *(const float4*)(xa + 4);
                float xv[8] = {v0.x, v0.y, v0.z, v0.w, v1.x, v1.y, v1.z, v1.w};
#pragma unroll
                for (int j = 0; j < 8; ++j) {
                    unsigned short h = f2bf(xv[j]);
                    ah[mt][j] = (short)h;
                    al[mt][j] = (short)f2bf(xv[j] - bf2f(h));
                }
            }
#pragma unroll
            for (int mt = 0; mt < 2; ++mt)
#pragma unroll
                for (int nt = 0; nt < 4; ++nt) {
                    acc[bt][mt][nt] = __builtin_amdgcn_mfma_f32_16x16x32_bf16(ah[mt], bh[nt], acc[bt][mt][nt], 0, 0, 0);
                    acc[bt][mt][nt] = __builtin_amdgcn_mfma_f32_16x16x32_bf16(al[mt], bh[nt], acc[bt][mt][nt], 0, 0, 0);
                    acc[bt][mt][nt] = __builtin_amdgcn_mfma_f32_16x16x32_bf16(ah[mt], bl[nt], acc[bt][mt][nt], 0, 0, 0);
                }
        }
    }

    // store natural fp32: C/D map col=ln, row=quad*4+r; 16 ln-lanes = 64B lines
    for (int bt = 0; bt < nbt; ++bt)
#pragma unroll
        for (int mt = 0; mt < 2; ++mt)
#pragma unroll
            for (int nt = 0; nt < 4; ++nt) {
                const int D = nt * 16 + ln;
#pragma unroll
                for (int r = 0; r < 4; ++r) {
                    const int row = bt * 128 + wave * 32 + mt * 16 + quad * 4 + r;
                    p[((size_t)(row * PRE + kk) * NEXT + K) * DOUT + D] = acc[bt][mt][nt][r];
                }
            }
}

// ---------------- Routing: 3 fused passes over fp32 p -------------------------
// One 1024-thr block (16 waves) per b. Wave w: k = i*16+w, i=0..3 -> 2x TLP vs
// R7. pv single-buffered (32 regs) + qa (32) + qsum in LDS: live ~90 regs ->
// NO spill (R7's WRITE=72MB killer). Load j: float4 idx k*512 + j*64 + lane ->
// K = j*4+(lane>>4), D-chunk m = lane&15; 1KB coalesced per instruction.
// 16-wave partials reduced in 64 KB LDS via two-phase (store / add) to keep
// LDS at 72 KB. Logits via running-sum Q (linearity of b in q).
__global__ __launch_bounds__(1024, 1) void route_kernel(const float* __restrict__ p,
                                                        float* __restrict__ out,
                                                        int b0)
{
    __shared__ float qpart[8 * 2048];   // 64 KB: region per wave-pair
    __shared__ float qsum[2048];        // 8 KB running Q
    const int b    = blockIdx.x;
    const int t    = threadIdx.x;
    const int w    = t >> 6;      // 0..15
    const int lane = t & 63;
    const int g    = lane >> 4;   // 0..3
    const int m    = lane & 15;   // 0..15
    const float4* pb = (const float4*)(p + (size_t)b * (PRE * NEXT * DOUT));

    for (int idx = t; idx < 2048; idx += 1024) qsum[idx] = 0.f;
    __syncthreads();

    for (int pass = 0; pass < 3; ++pass) {
        float4 qa[8];
#pragma unroll
        for (int j = 0; j < 8; ++j) qa[j] = (float4){0.f, 0.f, 0.f, 0.f};

#pragma unroll
        for (int i = 0; i < 4; ++i) {
            float4 pv[8];
            const size_t sb = (size_t)(i * 16 + w) * 512;
#pragma unroll
            for (int j = 0; j < 8; ++j) pv[j] = pb[sb + j * 64 + lane];

            float c[8];
            if (pass == 0) {
#pragma unroll
                for (int j = 0; j < 8; ++j) c[j] = 1.0f / 32.0f;
            } else {
                // logits = p . Q (running sum from LDS, b128 reads)
#pragma unroll
                for (int j = 0; j < 8; ++j) {
                    float4 qv = *(const float4*)&qsum[(j * 4 + g) * 64 + m * 4];
                    float d = pv[j].x * qv.x + pv[j].y * qv.y
                            + pv[j].z * qv.z + pv[j].w * qv.w;
                    d += __shfl_xor(d, 1);
                    d += __shfl_xor(d, 2);
                    d += __shfl_xor(d, 4);
                    d += __shfl_xor(d, 8);
                    c[j] = d;
                }
                float mx = c[0];
#pragma unroll
                for (int j = 1; j < 8; ++j) mx = fmaxf(mx, c[j]);
                mx = fmaxf(mx, __shfl_xor(mx, 16));
                mx = fmaxf(mx, __shfl_xor(mx, 32));
                float s = 0.f;
#pragma unroll
                for (int j = 0; j < 8; ++j) { c[j] = __expf(c[j] - mx); s += c[j]; }
                s += __shfl_xor(s, 16);
                s += __shfl_xor(s, 32);
                float inv = 1.0f / s;
#pragma unroll
                for (int j = 0; j < 8; ++j) c[j] *= inv;
            }
#pragma unroll
            for (int j = 0; j < 8; ++j) {
                qa[j].x += c[j] * pv[j].x;
                qa[j].y += c[j] * pv[j].y;
                qa[j].z += c[j] * pv[j].z;
                qa[j].w += c[j] * pv[j].w;
            }
        }
        // two-phase 16-wave reduce into 8 LDS regions
        if (w < 8) {
#pragma unroll
            for (int j = 0; j < 8; ++j)
                *(float4*)&qpart[w * 2048 + (j * 4 + g) * 64 + m * 4] = qa[j];
        }
        __syncthreads();
        if (w >= 8) {
#pragma unroll
            for (int j = 0; j < 8; ++j) {
                float* dst = &qpart[(w - 8) * 2048 + (j * 4 + g) * 64 + m * 4];
                float4 cur = *(const float4*)dst;
                cur.x += qa[j].x; cur.y += qa[j].y; cur.z += qa[j].z; cur.w += qa[j].w;
                *(float4*)dst = cur;
            }
        }
        __syncthreads();

        // tree-sum over 8 regions + squash; thread t<512 owns (K=t>>4, ch=t&15)
        if (t < 512) {
            const int Kq = t >> 4, ch = t & 15;
            float4 v = (float4){0.f, 0.f, 0.f, 0.f};
#pragma unroll
            for (int ww = 0; ww < 8; ++ww) {
                float4 s4 = *(const float4*)&qpart[ww * 2048 + Kq * 64 + ch * 4];
                v.x += s4.x; v.y += s4.y; v.z += s4.z; v.w += s4.w;
            }
            float s2 = v.x * v.x + v.y * v.y + v.z * v.z + v.w * v.w;
            s2 += __shfl_xor(s2, 1);
            s2 += __shfl_xor(s2, 2);
            s2 += __shfl_xor(s2, 4);
            s2 += __shfl_xor(s2, 8);
            float fsc = s2 / ((1.f + s2) * sqrtf(s2 + 1e-8f));
            v.x *= fsc; v.y *= fsc; v.z *= fsc; v.w *= fsc;
            if (pass < 2) {
                float* qd = &qsum[Kq * 64 + ch * 4];
                qd[0] += v.x; qd[1] += v.y; qd[2] += v.z; qd[3] += v.w;
            } else {
                *(float4*)(out + (size_t)(b0 + b) * 2048 + Kq * 64 + ch * 4) = v;
            }
        }
        if (pass < 2) __syncthreads();
    }
}

extern "C" void kernel_launch(void* const* d_in, const int* in_sizes, int n_in,
                              void* d_out, int out_size, void* d_ws, size_t ws_size,
                              hipStream_t stream) {
    const float* x = (const float*)d_in[0];
    const float* W = (const float*)d_in[1];
    float* out = (float*)d_out;
    float* p   = (float*)d_ws;    // p owns the whole workspace

    const int chunk = (ws_size >= (size_t)134217728) ? 256 : 128;
    const int nbt   = chunk / 128;

    for (int b0 = 0; b0 < BATCH; b0 += chunk) {
        gemm_kernel<<<dim3(NEXT, PRE), 256, 0, stream>>>(x, W, p, b0, nbt);
        route_kernel<<<chunk, 1024, 0, stream>>>(p, out, b0);
    }
}